// Round 6
// baseline (95.403 us; speedup 1.0000x reference)
//
#include <hip/hip_runtime.h>

// Softmax over last axis, rows=2048, cols=32000, fp32 in/out.
// Reference: e^x / sum(e^x), no max subtraction (inputs in [0,1)).
//
// Single-pass per row; 256 blocks x 8 rows, software-pipelined:
//   iter r: [issue row r+1 nontemporal loads] -> [fire row r stores]
//           -> [exp+reduce row r+1] -> raw barrier -> inv(r+1)
// Loads precede stores in issue order, so consuming loads waits only on the
// loads (in-order vmcnt retirement). The per-row barrier is a RAW
// "s_waitcnt lgkmcnt(0); s_barrier" (NOT __syncthreads, which drains
// vmcnt(0) and would stall every row on its store drain) -- stores stay in
// flight across rows, keeping read+write streams concurrently on the HBM bus.
// wsum is parity-double-buffered: each buffer's read -> next rewrite is
// separated by the intervening row's barrier, so one barrier/row is race-free.

#define SM_THREADS 1024
#define SM_V 32000
#define SM_FULL 7             // 7 * 1024 = 7168 full-coverage float4 iters
#define SM_REM 832            // 8000 - 7168 remainder float4s
#define SM_RPB 8              // rows per block

typedef float f32x4 __attribute__((ext_vector_type(4)));

// LDS-only barrier: waits ds ops, does NOT drain vmcnt (stores keep flying).
// "memory" clobber orders the preceding LDS write and following LDS reads.
#define LDS_BARRIER() asm volatile("s_waitcnt lgkmcnt(0)\n\ts_barrier" ::: "memory")

__device__ __forceinline__ void load_row(const float* __restrict__ in,
                                         size_t base, int tid, f32x4 x[8]) {
    const f32x4* __restrict__ inrow = reinterpret_cast<const f32x4*>(in + base);
    #pragma unroll
    for (int k = 0; k < SM_FULL; ++k)
        x[k] = __builtin_nontemporal_load(&inrow[tid + k * SM_THREADS]);
    if (tid < SM_REM)
        x[7] = __builtin_nontemporal_load(&inrow[tid + SM_FULL * SM_THREADS]);
}

__device__ __forceinline__ float exp_row(const f32x4 x[8], f32x4 e[8], int tid) {
    float lsum = 0.0f;
    #pragma unroll
    for (int k = 0; k < SM_FULL; ++k) {
        f32x4 ev;
        ev.x = __expf(x[k].x);
        ev.y = __expf(x[k].y);
        ev.z = __expf(x[k].z);
        ev.w = __expf(x[k].w);
        e[k] = ev;
        lsum += (ev.x + ev.y) + (ev.z + ev.w);
    }
    if (tid < SM_REM) {
        f32x4 ev;
        ev.x = __expf(x[7].x);
        ev.y = __expf(x[7].y);
        ev.z = __expf(x[7].z);
        ev.w = __expf(x[7].w);
        e[7] = ev;
        lsum += (ev.x + ev.y) + (ev.z + ev.w);
    }
    return lsum;
}

__device__ __forceinline__ void store_row(float* __restrict__ out, size_t base,
                                          int tid, const f32x4 e[8], float inv) {
    f32x4* __restrict__ outrow = reinterpret_cast<f32x4*>(out + base);
    #pragma unroll
    for (int k = 0; k < SM_FULL; ++k) {
        f32x4 o;
        o.x = e[k].x * inv;
        o.y = e[k].y * inv;
        o.z = e[k].z * inv;
        o.w = e[k].w * inv;
        __builtin_nontemporal_store(o, &outrow[tid + k * SM_THREADS]);
    }
    if (tid < SM_REM) {
        f32x4 o;
        o.x = e[7].x * inv;
        o.y = e[7].y * inv;
        o.z = e[7].z * inv;
        o.w = e[7].w * inv;
        __builtin_nontemporal_store(o, &outrow[tid + SM_FULL * SM_THREADS]);
    }
}

__global__ __launch_bounds__(SM_THREADS, 1)
void softmax_rowwise_kernel(const float* __restrict__ in,
                            float* __restrict__ out) {
    const int tid = threadIdx.x;
    const int wave = tid >> 6;
    const int lane = tid & 63;

    __shared__ float wsum[2][SM_THREADS / 64];

    const int row0 = blockIdx.x * SM_RPB;

    f32x4 x[8], e[8];

    // Prologue: row 0 of this block.
    load_row(in, (size_t)row0 * SM_V, tid, x);
    float lsum = exp_row(x, e, tid);

    #pragma unroll
    for (int off = 32; off > 0; off >>= 1)
        lsum += __shfl_down(lsum, off, 64);
    if (lane == 0) wsum[0][wave] = lsum;
    LDS_BARRIER();
    float total = 0.0f;
    #pragma unroll
    for (int i = 0; i < SM_THREADS / 64; ++i)
        total += wsum[0][i];
    float inv = 1.0f / total;

    for (int r = 0; r < SM_RPB; ++r) {
        f32x4 xn[8];
        const bool more = (r + 1 < SM_RPB);

        // 1) Issue next row's loads FIRST (older than stores in vmcnt order).
        if (more)
            load_row(in, (size_t)(row0 + r + 1) * SM_V, tid, xn);

        // 2) Fire-and-forget stores of current row (never waited on).
        store_row(out, (size_t)(row0 + r) * SM_V, tid, e, inv);

        // 3) Consume next row's loads, reduce, LDS-only barrier.
        if (more) {
            lsum = exp_row(xn, e, tid);
            #pragma unroll
            for (int off = 32; off > 0; off >>= 1)
                lsum += __shfl_down(lsum, off, 64);
            const int p = (r + 1) & 1;
            if (lane == 0) wsum[p][wave] = lsum;
            LDS_BARRIER();
            total = 0.0f;
            #pragma unroll
            for (int i = 0; i < SM_THREADS / 64; ++i)
                total += wsum[p][i];
            inv = 1.0f / total;
        }
    }
}

extern "C" void kernel_launch(void* const* d_in, const int* in_sizes, int n_in,
                              void* d_out, int out_size, void* d_ws, size_t ws_size,
                              hipStream_t stream) {
    (void)n_in; (void)d_ws; (void)ws_size; (void)out_size;
    const float* in = (const float*)d_in[0];
    float* out = (float*)d_out;
    const int rows = in_sizes[0] / SM_V;               // 2048
    const int blocks = rows / SM_RPB;                  // 256
    softmax_rowwise_kernel<<<dim3(blocks), dim3(SM_THREADS), 0, stream>>>(in, out);
}

// Round 7
// 91.606 us; speedup vs baseline: 1.0415x; 1.0415x over previous
//
#include <hip/hip_runtime.h>

// Softmax over last axis, rows=2048, cols=32000, fp32 in/out.
// Reference: e^x / sum(e^x), no max subtraction (inputs in [0,1)).
//
// BEST MEASURED STRUCTURE (R2, 91.8 us = 5.71 TB/s effective):
// Single-pass: one 1024-thread block per row; each thread caches its 32
// exp() values in registers (8 x float4) -> input read once, output written
// once (524 MB total, provably minimal). Nontemporal load/store: both
// streams are touch-once, bypassing L2/L3 avoids the two 262 MB streams
// thrashing the 256 MB L3 (104 -> 91.8 us).
//
// NOTE (R3-R6 post-mortems): every explicit phase-overlap variant LOST to
// this plain structure -- 512thr/2-blocks-per-CU (93.2), 8-rows-per-block
// loop (99.0), loads-before-stores pipeline (94.0), LDS-only s_barrier that
// keeps stores in flight (95.4). With 2048 independent blocks at staggered
// phases across 256 CUs, the HBM bus already sees a mixed read+write stream;
// intra-block pipelining only adds overhead. Keep it simple.

#define SM_THREADS 1024
#define SM_V 32000
#define SM_FULL 7             // 7 * 1024 = 7168 full-coverage float4 iters
#define SM_REM 832            // 8000 - 7168 remainder float4s

typedef float f32x4 __attribute__((ext_vector_type(4)));

__global__ __launch_bounds__(SM_THREADS, 1)
void softmax_rowwise_kernel(const float* __restrict__ in,
                            float* __restrict__ out) {
    const int row = blockIdx.x;
    const size_t base = (size_t)row * SM_V;
    const f32x4* __restrict__ inrow  = reinterpret_cast<const f32x4*>(in + base);
    f32x4* __restrict__       outrow = reinterpret_cast<f32x4*>(out + base);
    const int tid = threadIdx.x;

    f32x4 e[8];
    float lsum = 0.0f;

    #pragma unroll
    for (int k = 0; k < SM_FULL; ++k) {
        f32x4 x = __builtin_nontemporal_load(&inrow[tid + k * SM_THREADS]);
        f32x4 ev;
        ev.x = __expf(x.x);
        ev.y = __expf(x.y);
        ev.z = __expf(x.z);
        ev.w = __expf(x.w);
        e[k] = ev;
        lsum += (ev.x + ev.y) + (ev.z + ev.w);
    }
    if (tid < SM_REM) {
        f32x4 x = __builtin_nontemporal_load(&inrow[tid + SM_FULL * SM_THREADS]);
        f32x4 ev;
        ev.x = __expf(x.x);
        ev.y = __expf(x.y);
        ev.z = __expf(x.z);
        ev.w = __expf(x.w);
        e[7] = ev;
        lsum += (ev.x + ev.y) + (ev.z + ev.w);
    }

    // Wave-level (64-lane) shuffle reduction.
    #pragma unroll
    for (int off = 32; off > 0; off >>= 1)
        lsum += __shfl_down(lsum, off, 64);

    // Block-level reduction across the 16 waves via LDS.
    __shared__ float wsum[SM_THREADS / 64];
    const int wave = tid >> 6;
    const int lane = tid & 63;
    if (lane == 0) wsum[wave] = lsum;
    __syncthreads();

    float total = 0.0f;
    #pragma unroll
    for (int i = 0; i < SM_THREADS / 64; ++i)
        total += wsum[i];   // broadcast LDS reads: conflict-free

    const float inv = 1.0f / total;

    #pragma unroll
    for (int k = 0; k < SM_FULL; ++k) {
        f32x4 ev = e[k];
        f32x4 o;
        o.x = ev.x * inv;
        o.y = ev.y * inv;
        o.z = ev.z * inv;
        o.w = ev.w * inv;
        __builtin_nontemporal_store(o, &outrow[tid + k * SM_THREADS]);
    }
    if (tid < SM_REM) {
        f32x4 ev = e[7];
        f32x4 o;
        o.x = ev.x * inv;
        o.y = ev.y * inv;
        o.z = ev.z * inv;
        o.w = ev.w * inv;
        __builtin_nontemporal_store(o, &outrow[tid + SM_FULL * SM_THREADS]);
    }
}

extern "C" void kernel_launch(void* const* d_in, const int* in_sizes, int n_in,
                              void* d_out, int out_size, void* d_ws, size_t ws_size,
                              hipStream_t stream) {
    (void)n_in; (void)d_ws; (void)ws_size; (void)out_size;
    const float* in = (const float*)d_in[0];
    float* out = (float*)d_out;
    const int rows = in_sizes[0] / SM_V;   // 2048
    softmax_rowwise_kernel<<<dim3(rows), dim3(SM_THREADS), 0, stream>>>(in, out);
}